// Round 18
// baseline (2375.063 us; speedup 1.0000x reference)
//
#include <hip/hip_runtime.h>
#include <hip/hip_fp16.h>
#include <math.h>

#define NB 64
#define NQ 300
#define NP 6
#define ND 256
#define NF 512
#define NCL 396
#define NT 10

// fp16 weight workspace layout (element offsets in halves)
#define IPW_OFF 0
#define INW_OFF 262144
#define OW_OFF  655360
#define L1W_OFF 786432
#define L2W_OFF 1048576
#define C1W_OFF 1310720
#define C2W_OFF 1441792
#define TOTW    1644544
#define CONV_BLOCKS 803
#define POOL_ROWS 65536

typedef float f4 __attribute__((ext_vector_type(4)));

__device__ __forceinline__ float wred(float s) {
    #pragma unroll
    for (int o = 32; o; o >>= 1) s += __shfl_down(s, o, 64);
    return s;
}

__device__ __forceinline__ float dot8h(f4 wv, f4 xlo, f4 xhi) {
    const __half2* hp = reinterpret_cast<const __half2*>(&wv);
    float2 p0 = __half22float2(hp[0]);
    float2 p1 = __half22float2(hp[1]);
    float2 p2 = __half22float2(hp[2]);
    float2 p3 = __half22float2(hp[3]);
    return p0.x * xlo.x + p0.y * xlo.y + p1.x * xlo.z + p1.y * xlo.w
         + p2.x * xhi.x + p2.y * xhi.y + p3.x * xhi.z + p3.y * xhi.w;
}

// generation-based 4-sibling barrier: each use adds 1/sibling; instance n
// (1-based across the whole kernel run) waits for flag >= 4n.
__device__ __forceinline__ void qsyncg(int* flag, int tid, int target) {
    __syncthreads();
    if (tid == 0) {
        __threadfence();
        __hip_atomic_fetch_add(flag, 1, __ATOMIC_ACQ_REL, __HIP_MEMORY_SCOPE_AGENT);
        while (__hip_atomic_load(flag, __ATOMIC_ACQUIRE, __HIP_MEMORY_SCOPE_AGENT) < target)
            __builtin_amdgcn_s_sleep(2);
    }
    __syncthreads();
}

// ---------------------------------------------------------------------------
// K1 (R13, + zeroing of BOTH flag arrays)
// ---------------------------------------------------------------------------
__global__ __launch_bounds__(256) void pool_cls_kernel(
    const float* __restrict__ pred, const float* __restrict__ hs,
    const float* __restrict__ f0, const float* __restrict__ f1,
    const float* __restrict__ f2, const float* __restrict__ f3,
    const float* __restrict__ ipw, const float* __restrict__ inw,
    const float* __restrict__ ow, const float* __restrict__ l1w,
    const float* __restrict__ l2w, const float* __restrict__ c1w,
    const float* __restrict__ c2w,
    float* __restrict__ pooled, float* __restrict__ tokG,
    float* __restrict__ biasW, __half* __restrict__ wH,
    int* __restrict__ flagW, int* __restrict__ pflagW)
{
    const int bid = blockIdx.x;
    const int tid = threadIdx.x;
    __shared__ float shm[1824];

    if (bid < NB) {
        const int b = bid;
        if (tid < 16) { flagW[b * 16 + tid] = 0; pflagW[b * 16 + tid] = 0; }
        float* maskL = shm;
        float* countsL = shm + 1800;
        for (int i = tid; i < NQ * NP; i += 256) {
            float x = pred[(size_t)b * NQ * NP + i];
            float sg = 1.f / (1.f + expf(-x));
            maskL[i] = (sg > 0.3f) ? 1.f : 0.f;
        }
        __syncthreads();
        if (tid < NP) {
            float c = 0.f;
            for (int q = 0; q < NQ; q++) c += maskL[q * NP + tid];
            countsL[tid] = c;
        }
        __syncthreads();
        float acc[NP] = {0.f, 0.f, 0.f, 0.f, 0.f, 0.f};
        const float* hsb = hs + (size_t)b * NQ * ND + tid;
        for (int q = 0; q < NQ; q++) {
            float h = hsb[(size_t)q * ND];
            #pragma unroll
            for (int p = 0; p < NP; p++) acc[p] += maskL[q * NP + p] * h;
        }
        bool anyv = false;
        #pragma unroll
        for (int p = 0; p < NP; p++) anyv = anyv || (countsL[p] > 0.f);
        #pragma unroll
        for (int p = 0; p < NP; p++) {
            float cm = acc[p] / fmaxf(countsL[p], 1.f);
            if (p == 0 && !anyv) cm = hs[(size_t)b * NQ * ND + tid];
            tokG[(size_t)b * 2560 + p * ND + tid] = cm;
        }
        if (tid < 16) {
            float bv = 0.f;
            if (tid < NP) {
                bool v = countsL[tid] > 0.f;
                if (tid == 0 && !anyv) v = true;
                bv = v ? 0.f : -1e30f;
            }
            biasW[b * 16 + tid] = bv;
        }
        return;
    }

    if (bid >= NB + POOL_ROWS) {
        const int cid = bid - (NB + POOL_ROWS);
        size_t base = (size_t)cid * 2048 + (size_t)tid * 8;
        const float* src; size_t off;
        if      (base < INW_OFF) { src = ipw; off = IPW_OFF; }
        else if (base < OW_OFF)  { src = inw; off = INW_OFF; }
        else if (base < L1W_OFF) { src = ow;  off = OW_OFF;  }
        else if (base < L2W_OFF) { src = l1w; off = L1W_OFF; }
        else if (base < C1W_OFF) { src = l2w; off = L2W_OFF; }
        else if (base < C2W_OFF) { src = c1w; off = C1W_OFF; }
        else                     { src = c2w; off = C2W_OFF; }
        const f4* s4 = reinterpret_cast<const f4*>(src + (base - off));
        f4 a = s4[0], b2 = s4[1];
        union { __half2 h[4]; f4 v; } u;
        u.h[0] = __floats2half2_rn(a.x, a.y);
        u.h[1] = __floats2half2_rn(a.z, a.w);
        u.h[2] = __floats2half2_rn(b2.x, b2.y);
        u.h[3] = __floats2half2_rn(b2.z, b2.w);
        *reinterpret_cast<f4*>(wH + base) = u.v;
        return;
    }

    const int row = bid - NB;
    const int scale = row >> 14;
    const int rr = row & 16383;
    const int b = rr >> 8;
    const int d = rr & 255;
    const float* src;
    int n;
    switch (scale) {
        case 0: src = f0; n = 96 * 96; break;
        case 1: src = f1; n = 48 * 48; break;
        case 2: src = f2; n = 24 * 24; break;
        default: src = f3; n = 12 * 12; break;
    }
    const f4* p4 = reinterpret_cast<const f4*>(src + ((size_t)b * ND + d) * (size_t)n);
    int n4 = n >> 2;
    float s = 0.f;
    for (int i = tid; i < n4; i += 256) {
        f4 v = __builtin_nontemporal_load(&p4[i]);
        s += v.x + v.y + v.z + v.w;
    }
    s = wred(s);
    int wid = tid >> 6, lane = tid & 63;
    if (lane == 0) shm[wid] = s;
    __syncthreads();
    if (tid == 0) {
        float t = shm[0] + shm[1] + shm[2] + shm[3];
        pooled[((size_t)b * 4 + scale) * ND + d] = t / (float)n;
    }
}

// ---------------------------------------------------------------------------
// K2: column-split transformer (R13 logic) with iteration count for the
// profiling clone. iters=1, flags=flagW, outp=d_out  -> real run (R13-equal).
// iters=8, flags=pflagW, outp=scratch               -> profiling run.
// ---------------------------------------------------------------------------
__global__ __launch_bounds__(512) void xform_kernel(
    const float* __restrict__ pooled, float* tokG,
    const float* __restrict__ biasW, const __half* __restrict__ wH,
    const float* __restrict__ ipb, const float* __restrict__ inb,
    const float* __restrict__ ob, const float* __restrict__ l1b,
    const float* __restrict__ l2b,
    const float* __restrict__ n1w, const float* __restrict__ n1b,
    const float* __restrict__ n2w, const float* __restrict__ n2b,
    const float* __restrict__ c1b, const float* __restrict__ c2b,
    float* aoW, float* resW, float* h1W, float* hW,
    int iters, int* flagW, float* __restrict__ outp)
{
    const int b  = blockIdx.x >> 2;
    const int qt = blockIdx.x & 3;
    const int tid = threadIdx.x;
    const int lane = tid & 63;
    const int wv = tid >> 6;
    int* flags = flagW + b * 16;

    __shared__ __align__(16) float xs[2560];
    __shared__ __align__(16) float loc[1920];
    __shared__ __align__(16) float buf[5120];
    __shared__ __align__(16) float part[5120];
    __shared__ float sc[224];
    __shared__ float stats[32];
    __shared__ float biasK[16];

    const f4* xs4 = reinterpret_cast<const f4*>(xs);
    const f4* buf4 = reinterpret_cast<const f4*>(buf);

    for (int it = 0; it < iters; ++it) {
        const int tgt = 4 * (it + 1);
        __syncthreads();   // prev iteration's readers done before re-staging

        for (int i = tid; i < 1536; i += 512) xs[i] = tokG[(size_t)b * 2560 + i];
        for (int i = tid; i < 1024; i += 512) buf[i] = pooled[(size_t)b * 1024 + i];
        if (tid < 16) biasK[tid] = biasW[b * 16 + tid];
        __syncthreads();

        if (tid < 256) {
            const int i = tid >> 6, cl = tid & 63;
            const int c = qt * 64 + cl;
            const f4* w4 = reinterpret_cast<const f4*>(wH + IPW_OFF + ((size_t)(i * 256 + c)) * 256);
            float acc = 0.f;
            #pragma unroll 4
            for (int k8 = 0; k8 < 32; k8++)
                acc += dot8h(w4[k8], buf4[i * 64 + 2 * k8], buf4[i * 64 + 2 * k8 + 1]);
            tokG[(size_t)b * 2560 + (6 + i) * 256 + c] = acc + ipb[i * 256 + c];
        }
        qsyncg(&flags[0], tid, tgt);
        for (int i = tid + 1536; i < 2560; i += 512) xs[i] = tokG[(size_t)b * 2560 + i];
        __syncthreads();

        for (int l = 0; l < 2; l++) {
            if (tid < 384) {
                const int ks = tid / 192, cl = tid % 192;
                const int m = cl >> 6;
                const int gc = m * 256 + qt * 64 + (cl & 63);
                const f4* w4 = reinterpret_cast<const f4*>(wH + INW_OFF + ((size_t)l * 768 + gc) * 256 + ks * 128);
                float acc[NT];
                #pragma unroll
                for (int r = 0; r < NT; r++) acc[r] = 0.f;
                for (int k8 = 0; k8 < 16; k8++) {
                    f4 wv4 = w4[k8];
                    const int xi = ks * 32 + 2 * k8;
                    #pragma unroll
                    for (int r = 0; r < NT; r++)
                        acc[r] += dot8h(wv4, xs4[r * 64 + xi], xs4[r * 64 + xi + 1]);
                }
                #pragma unroll
                for (int r = 0; r < NT; r++) part[ks * 1920 + r * 192 + cl] = acc[r];
            }
            __syncthreads();
            for (int i = tid; i < 1920; i += 512) {
                int r = i / 192, cl = i - r * 192;
                int m = cl >> 6, gc = m * 256 + qt * 64 + (cl & 63);
                loc[i] = part[i] + part[1920 + i] + inb[l * 768 + gc];
            }
            __syncthreads();

            if (tid < 200) {
                int hl = tid / 100, rem = tid - 100 * hl;
                int qr = rem / 10, kr = rem - 10 * qr;
                const float* qp = &loc[qr * 192 + hl * 32];
                const float* kp = &loc[kr * 192 + 64 + hl * 32];
                float s = 0.f;
                #pragma unroll
                for (int d = 0; d < 32; d++) s += qp[d] * kp[d];
                sc[tid] = s * 0.17677669529663687f + biasK[kr];
            }
            __syncthreads();
            if (tid < 20) {
                float* row = &sc[tid * 10];
                float m = row[0];
                #pragma unroll
                for (int k = 1; k < 10; k++) m = fmaxf(m, row[k]);
                float ss = 0.f;
                #pragma unroll
                for (int k = 0; k < 10; k++) { float e = expf(row[k] - m); row[k] = e; ss += e; }
                float inv = 1.f / ss;
                #pragma unroll
                for (int k = 0; k < 10; k++) row[k] *= inv;
            }
            __syncthreads();

            for (int idx = tid; idx < 640; idx += 512) {
                int hl = idx / 320, rem = idx - 320 * hl;
                int r = rem >> 5, c = rem & 31;
                float s = 0.f;
                #pragma unroll
                for (int kr = 0; kr < 10; kr++)
                    s += sc[hl * 100 + r * 10 + kr] * loc[kr * 192 + 128 + hl * 32 + c];
                aoW[(size_t)b * 2560 + r * 256 + qt * 64 + hl * 32 + c] = s;
            }
            qsyncg(&flags[1 + l * 4], tid, tgt);
            for (int i = tid; i < 2560; i += 512) buf[i] = aoW[(size_t)b * 2560 + i];
            __syncthreads();

            if (tid < 256) {
                const int ks = tid >> 6, cl = tid & 63;
                const int gc = qt * 64 + cl;
                const f4* w4 = reinterpret_cast<const f4*>(wH + OW_OFF + ((size_t)l * 256 + gc) * 256 + ks * 64);
                float acc[NT];
                #pragma unroll
                for (int r = 0; r < NT; r++) acc[r] = 0.f;
                for (int k8 = 0; k8 < 8; k8++) {
                    f4 wv4 = w4[k8];
                    const int xi = ks * 16 + 2 * k8;
                    #pragma unroll
                    for (int r = 0; r < NT; r++)
                        acc[r] += dot8h(wv4, buf4[r * 64 + xi], buf4[r * 64 + xi + 1]);
                }
                #pragma unroll
                for (int r = 0; r < NT; r++) part[ks * 640 + r * 64 + cl] = acc[r];
            }
            __syncthreads();
            for (int i = tid; i < 640; i += 512) {
                int r = i >> 6, cl = i & 63, gc = qt * 64 + cl;
                float v = part[i] + part[640 + i] + part[1280 + i] + part[1920 + i]
                        + ob[l * 256 + gc] + xs[r * 256 + gc];
                resW[(size_t)b * 2560 + r * 256 + gc] = v;
            }
            qsyncg(&flags[2 + l * 4], tid, tgt);
            for (int i = tid; i < 2560; i += 512) buf[i] = resW[(size_t)b * 2560 + i];
            __syncthreads();

            for (int r = wv; r < NT; r += 8) {
                float v0 = buf[r * 256 + lane], v1 = buf[r * 256 + 64 + lane];
                float v2 = buf[r * 256 + 128 + lane], v3 = buf[r * 256 + 192 + lane];
                float s = wred(v0 + v1 + v2 + v3);
                float q = wred(v0 * v0 + v1 * v1 + v2 * v2 + v3 * v3);
                if (lane == 0) {
                    float m = s * (1.f / 256.f);
                    stats[r] = m;
                    stats[16 + r] = rsqrtf(fmaxf(q * (1.f / 256.f) - m * m, 0.f) + 1e-5f);
                }
            }
            __syncthreads();
            for (int i = tid; i < 2560; i += 512) {
                int r = i >> 8, c = i & 255;
                xs[i] = (buf[i] - stats[r]) * stats[16 + r] * n1w[l * 256 + c] + n1b[l * 256 + c];
            }
            __syncthreads();

            {
                const int ks = tid >> 7, cl = tid & 127;
                const int gc = qt * 128 + cl;
                const f4* w4 = reinterpret_cast<const f4*>(wH + L1W_OFF + ((size_t)l * 512 + gc) * 256 + ks * 64);
                float acc[NT];
                #pragma unroll
                for (int r = 0; r < NT; r++) acc[r] = 0.f;
                for (int k8 = 0; k8 < 8; k8++) {
                    f4 wv4 = w4[k8];
                    const int xi = ks * 16 + 2 * k8;
                    #pragma unroll
                    for (int r = 0; r < NT; r++)
                        acc[r] += dot8h(wv4, xs4[r * 64 + xi], xs4[r * 64 + xi + 1]);
                }
                __syncthreads();
                #pragma unroll
                for (int r = 0; r < NT; r++) buf[ks * 1280 + r * 128 + cl] = acc[r];
            }
            __syncthreads();
            for (int i = tid; i < 1280; i += 512) {
                int r = i >> 7, cl = i & 127, gc = qt * 128 + cl;
                float h = fmaxf(buf[i] + buf[1280 + i] + buf[2560 + i] + buf[3840 + i]
                              + l1b[l * 512 + gc], 0.f);
                h1W[(size_t)b * 5120 + r * 512 + gc] = h;
            }
            qsyncg(&flags[3 + l * 4], tid, tgt);
            for (int i = tid; i < 5120; i += 512) buf[i] = h1W[(size_t)b * 5120 + i];
            __syncthreads();

            {
                const int ks = tid >> 6, cl = tid & 63;
                const int gc = qt * 64 + cl;
                const f4* w4 = reinterpret_cast<const f4*>(wH + L2W_OFF + ((size_t)l * 256 + gc) * 512 + ks * 64);
                float acc[NT];
                #pragma unroll
                for (int r = 0; r < NT; r++) acc[r] = 0.f;
                for (int k8 = 0; k8 < 8; k8++) {
                    f4 wv4 = w4[k8];
                    const int xi = ks * 16 + 2 * k8;
                    #pragma unroll
                    for (int r = 0; r < NT; r++)
                        acc[r] += dot8h(wv4, buf4[r * 128 + xi], buf4[r * 128 + xi + 1]);
                }
                #pragma unroll
                for (int r = 0; r < NT; r++) part[ks * 640 + r * 64 + cl] = acc[r];
            }
            __syncthreads();
            for (int i = tid; i < 640; i += 512) {
                int r = i >> 6, cl = i & 63, gc = qt * 64 + cl;
                float v = part[i] + part[640 + i] + part[1280 + i] + part[1920 + i]
                        + part[2560 + i] + part[3200 + i] + part[3840 + i] + part[4480 + i]
                        + l2b[l * 256 + gc] + xs[r * 256 + gc];
                resW[(size_t)b * 2560 + r * 256 + gc] = v;
            }
            qsyncg(&flags[4 + l * 4], tid, tgt);
            for (int i = tid; i < 2560; i += 512) buf[i] = resW[(size_t)b * 2560 + i];
            __syncthreads();

            for (int r = wv; r < NT; r += 8) {
                float v0 = buf[r * 256 + lane], v1 = buf[r * 256 + 64 + lane];
                float v2 = buf[r * 256 + 128 + lane], v3 = buf[r * 256 + 192 + lane];
                float s = wred(v0 + v1 + v2 + v3);
                float q = wred(v0 * v0 + v1 * v1 + v2 * v2 + v3 * v3);
                if (lane == 0) {
                    float m = s * (1.f / 256.f);
                    stats[r] = m;
                    stats[16 + r] = rsqrtf(fmaxf(q * (1.f / 256.f) - m * m, 0.f) + 1e-5f);
                }
            }
            __syncthreads();
            for (int i = tid; i < 2560; i += 512) {
                int r = i >> 8, c = i & 255;
                xs[i] = (buf[i] - stats[r]) * stats[16 + r] * n2w[l * 256 + c] + n2b[l * 256 + c];
            }
            __syncthreads();
        }

        if (tid < 256) {
            float len = 0.f, s = 0.f;
            #pragma unroll
            for (int r = 0; r < NT; r++) {
                float v = (biasK[r] == 0.f) ? 1.f : 0.f;
                len += v;
                s += v * xs[r * 256 + tid];
            }
            buf[tid] = s / fmaxf(len, 1.f);
        }
        __syncthreads();

        if (tid < 256) {
            const int ks = tid >> 7, cl = tid & 127;
            const int gc = qt * 128 + cl;
            const f4* w4 = reinterpret_cast<const f4*>(wH + C1W_OFF + (size_t)gc * 256 + ks * 128);
            float acc = 0.f;
            #pragma unroll 4
            for (int k8 = 0; k8 < 16; k8++)
                acc += dot8h(w4[k8], buf4[ks * 32 + 2 * k8], buf4[ks * 32 + 2 * k8 + 1]);
            part[ks * 128 + cl] = acc;
        }
        __syncthreads();
        if (tid < 128) {
            const int gc = qt * 128 + tid;
            hW[(size_t)b * 512 + gc] = fmaxf(part[tid] + part[128 + tid] + c1b[gc], 0.f);
        }
        qsyncg(&flags[9], tid, tgt);
        for (int i = tid; i < 512; i += 512) buf[i] = hW[(size_t)b * 512 + i];
        __syncthreads();

        if (tid < 99) {
            const int o = qt * 99 + tid;
            const f4* w4 = reinterpret_cast<const f4*>(wH + C2W_OFF + (size_t)o * 512);
            float acc = 0.f;
            #pragma unroll 4
            for (int k8 = 0; k8 < 64; k8++)
                acc += dot8h(w4[k8], buf4[2 * k8], buf4[2 * k8 + 1]);
            outp[(size_t)b * NCL + o] = acc + c2b[o];
        }
    }
}

// ---------------------------------------------------------------------------
extern "C" void kernel_launch(void* const* d_in, const int* in_sizes, int n_in,
                              void* d_out, int out_size, void* d_ws, size_t ws_size,
                              hipStream_t stream)
{
    const float* pred = (const float*)d_in[0];
    const float* hs   = (const float*)d_in[1];
    const float* f0   = (const float*)d_in[2];
    const float* f1   = (const float*)d_in[3];
    const float* f2   = (const float*)d_in[4];
    const float* f3   = (const float*)d_in[5];
    const float* ipw  = (const float*)d_in[6];
    const float* ipb  = (const float*)d_in[7];
    const float* inw  = (const float*)d_in[8];
    const float* inb  = (const float*)d_in[9];
    const float* ow   = (const float*)d_in[10];
    const float* ob   = (const float*)d_in[11];
    const float* l1w  = (const float*)d_in[12];
    const float* l1b  = (const float*)d_in[13];
    const float* l2w  = (const float*)d_in[14];
    const float* l2b  = (const float*)d_in[15];
    const float* ln1w = (const float*)d_in[16];
    const float* ln1b = (const float*)d_in[17];
    const float* ln2w = (const float*)d_in[18];
    const float* ln2b = (const float*)d_in[19];
    const float* c1w  = (const float*)d_in[20];
    const float* c1b  = (const float*)d_in[21];
    const float* c2w  = (const float*)d_in[22];
    const float* c2b  = (const float*)d_in[23];

    float* ws = (float*)d_ws;
    float* pooled = ws;
    float* tokG   = pooled + NB * 4 * ND;
    float* biasW  = tokG + NB * 2560;
    __half* wH    = (__half*)(biasW + 1024);
    float* aoW    = (float*)(wH + TOTW);
    float* resW   = aoW + NB * 2560;
    float* h1W    = resW + NB * 2560;
    float* hW     = h1W + NB * 5120;
    int*   flagW  = (int*)(hW + NB * 512);        // 1024 ints
    int*   pflagW = flagW + 1024;                 // 1024 ints
    float* pout   = (float*)(pflagW + 1024);      // NB*NCL scratch

    pool_cls_kernel<<<NB + POOL_ROWS + CONV_BLOCKS, 256, 0, stream>>>(
        pred, hs, f0, f1, f2, f3, ipw, inw, ow, l1w, l2w, c1w, c2w,
        pooled, tokG, biasW, wH, flagW, pflagW);
    // real run (identical result to R13)
    xform_kernel<<<4 * NB, 512, 0, stream>>>(
        pooled, tokG, biasW, wH, ipb, inb, ob, l1b, l2b,
        ln1w, ln1b, ln2w, ln2b, c1b, c2b,
        aoW, resW, h1W, hW, 1, flagW, (float*)d_out);
    // profiling clone: 8 iterations, own flags, scratch output.
    // Pure recomputation of identical values -> deterministic.
    xform_kernel<<<4 * NB, 512, 0, stream>>>(
        pooled, tokG, biasW, wH, ipb, inb, ob, l1b, l2b,
        ln1w, ln1b, ln2w, ln2b, c1b, c2b,
        aoW, resW, h1W, hW, 8, pflagW, pout);
}

// Round 20
// 283.037 us; speedup vs baseline: 8.3913x; 8.3913x over previous
//
#include <hip/hip_runtime.h>
#include <hip/hip_fp16.h>
#include <math.h>

#define NB 64
#define NQ 300
#define NP 6
#define ND 256
#define NF 512
#define NCL 396
#define NT 10

// fp16 weight workspace layout (element offsets in halves)
#define IPW_OFF 0
#define INW_OFF 262144
#define OW_OFF  655360
#define L1W_OFF 786432
#define L2W_OFF 1048576
#define C1W_OFF 1310720
#define C2W_OFF 1441792
#define TOTW    1644544
#define CONV_BLOCKS 803
#define POOL_ROWS 65536

typedef float f4 __attribute__((ext_vector_type(4)));

__device__ __forceinline__ float wred(float s) {
    #pragma unroll
    for (int o = 32; o; o >>= 1) s += __shfl_down(s, o, 64);
    return s;
}

__device__ __forceinline__ float dot8h(f4 wv, f4 xlo, f4 xhi) {
    const __half2* hp = reinterpret_cast<const __half2*>(&wv);
    float2 p0 = __half22float2(hp[0]);
    float2 p1 = __half22float2(hp[1]);
    float2 p2 = __half22float2(hp[2]);
    float2 p3 = __half22float2(hp[3]);
    return p0.x * xlo.x + p0.y * xlo.y + p1.x * xlo.z + p1.y * xlo.w
         + p2.x * xhi.x + p2.y * xhi.y + p3.x * xhi.z + p3.y * xhi.w;
}

// 4-sibling spin barrier (device scope; flags zeroed by K1 each call;
// siblings are XCD-local so flag+data traffic stays in one L2).
__device__ __forceinline__ void qsync(int* flag, int tid) {
    __syncthreads();
    if (tid == 0) {
        __threadfence();
        __hip_atomic_fetch_add(flag, 1, __ATOMIC_ACQ_REL, __HIP_MEMORY_SCOPE_AGENT);
        while (__hip_atomic_load(flag, __ATOMIC_ACQUIRE, __HIP_MEMORY_SCOPE_AGENT) < 4)
            __builtin_amdgcn_s_sleep(2);
    }
    __syncthreads();
}

// ---------------------------------------------------------------------------
// K1 (R13, unchanged): cls-pool + feat-pool + fp16 weight conversion.
// ---------------------------------------------------------------------------
__global__ __launch_bounds__(256) void pool_cls_kernel(
    const float* __restrict__ pred, const float* __restrict__ hs,
    const float* __restrict__ f0, const float* __restrict__ f1,
    const float* __restrict__ f2, const float* __restrict__ f3,
    const float* __restrict__ ipw, const float* __restrict__ inw,
    const float* __restrict__ ow, const float* __restrict__ l1w,
    const float* __restrict__ l2w, const float* __restrict__ c1w,
    const float* __restrict__ c2w,
    float* __restrict__ pooled, float* __restrict__ tokG,
    float* __restrict__ biasW, __half* __restrict__ wH,
    int* __restrict__ flagW)
{
    const int bid = blockIdx.x;
    const int tid = threadIdx.x;
    __shared__ float shm[1824];

    if (bid < NB) {
        const int b = bid;
        if (tid < 16) flagW[b * 16 + tid] = 0;
        float* maskL = shm;
        float* countsL = shm + 1800;
        for (int i = tid; i < NQ * NP; i += 256) {
            float x = pred[(size_t)b * NQ * NP + i];
            float sg = 1.f / (1.f + expf(-x));
            maskL[i] = (sg > 0.3f) ? 1.f : 0.f;
        }
        __syncthreads();
        if (tid < NP) {
            float c = 0.f;
            for (int q = 0; q < NQ; q++) c += maskL[q * NP + tid];
            countsL[tid] = c;
        }
        __syncthreads();
        float acc[NP] = {0.f, 0.f, 0.f, 0.f, 0.f, 0.f};
        const float* hsb = hs + (size_t)b * NQ * ND + tid;
        for (int q = 0; q < NQ; q++) {
            float h = hsb[(size_t)q * ND];
            #pragma unroll
            for (int p = 0; p < NP; p++) acc[p] += maskL[q * NP + p] * h;
        }
        bool anyv = false;
        #pragma unroll
        for (int p = 0; p < NP; p++) anyv = anyv || (countsL[p] > 0.f);
        #pragma unroll
        for (int p = 0; p < NP; p++) {
            float cm = acc[p] / fmaxf(countsL[p], 1.f);
            if (p == 0 && !anyv) cm = hs[(size_t)b * NQ * ND + tid];
            tokG[(size_t)b * 2560 + p * ND + tid] = cm;
        }
        if (tid < 16) {
            float bv = 0.f;
            if (tid < NP) {
                bool v = countsL[tid] > 0.f;
                if (tid == 0 && !anyv) v = true;
                bv = v ? 0.f : -1e30f;
            }
            biasW[b * 16 + tid] = bv;
        }
        return;
    }

    if (bid >= NB + POOL_ROWS) {
        const int cid = bid - (NB + POOL_ROWS);
        size_t base = (size_t)cid * 2048 + (size_t)tid * 8;
        const float* src; size_t off;
        if      (base < INW_OFF) { src = ipw; off = IPW_OFF; }
        else if (base < OW_OFF)  { src = inw; off = INW_OFF; }
        else if (base < L1W_OFF) { src = ow;  off = OW_OFF;  }
        else if (base < L2W_OFF) { src = l1w; off = L1W_OFF; }
        else if (base < C1W_OFF) { src = l2w; off = L2W_OFF; }
        else if (base < C2W_OFF) { src = c1w; off = C1W_OFF; }
        else                     { src = c2w; off = C2W_OFF; }
        const f4* s4 = reinterpret_cast<const f4*>(src + (base - off));
        f4 a = s4[0], b2 = s4[1];
        union { __half2 h[4]; f4 v; } u;
        u.h[0] = __floats2half2_rn(a.x, a.y);
        u.h[1] = __floats2half2_rn(a.z, a.w);
        u.h[2] = __floats2half2_rn(b2.x, b2.y);
        u.h[3] = __floats2half2_rn(b2.z, b2.w);
        *reinterpret_cast<f4*>(wH + base) = u.v;
        return;
    }

    const int row = bid - NB;
    const int scale = row >> 14;
    const int rr = row & 16383;
    const int b = rr >> 8;
    const int d = rr & 255;
    const float* src;
    int n;
    switch (scale) {
        case 0: src = f0; n = 96 * 96; break;
        case 1: src = f1; n = 48 * 48; break;
        case 2: src = f2; n = 24 * 24; break;
        default: src = f3; n = 12 * 12; break;
    }
    const f4* p4 = reinterpret_cast<const f4*>(src + ((size_t)b * ND + d) * (size_t)n);
    int n4 = n >> 2;
    float s = 0.f;
    for (int i = tid; i < n4; i += 256) {
        f4 v = __builtin_nontemporal_load(&p4[i]);
        s += v.x + v.y + v.z + v.w;
    }
    s = wred(s);
    int wid = tid >> 6, lane = tid & 63;
    if (lane == 0) shm[wid] = s;
    __syncthreads();
    if (tid == 0) {
        float t = shm[0] + shm[1] + shm[2] + shm[3];
        pooled[((size_t)b * 4 + scale) * ND + d] = t / (float)n;
    }
}

// ---------------------------------------------------------------------------
// K2: column-split transformer, 6 syncs, XCD-local siblings.
// b = blk & 63, qt = blk >> 6 -> siblings {b, b+64, b+128, b+192} share XCD.
// Exchanges are partial-sum only: ao and h1 never leave LDS.
// (R19 + AV-loop fix: 640 elements over 512 threads needs a strided loop.)
// ---------------------------------------------------------------------------
__global__ __launch_bounds__(512) void xform_kernel(
    const float* __restrict__ pooled, float* tokG,
    const float* __restrict__ biasW, const __half* __restrict__ wH,
    const float* __restrict__ ipb, const float* __restrict__ inb,
    const float* __restrict__ ob, const float* __restrict__ l1b,
    const float* __restrict__ l2b,
    const float* __restrict__ n1w, const float* __restrict__ n1b,
    const float* __restrict__ n2w, const float* __restrict__ n2b,
    const float* __restrict__ c1b, const float* __restrict__ c2b,
    float* opW, float* f2W, float* hW,
    int* flagW, float* __restrict__ out)
{
    const int b  = blockIdx.x & 63;   // XCD-local decode
    const int qt = blockIdx.x >> 6;
    const int tid = threadIdx.x;
    const int lane = tid & 63;
    const int wv = tid >> 6;
    int* flags = flagW + b * 16;

    __shared__ __align__(16) float xs[2560];    // full current x
    __shared__ __align__(16) float loc[1920];   // pld (prologue) / own q|k|v
    __shared__ __align__(16) float res[2560];   // resid / ct / h staging
    __shared__ __align__(16) float h1a[1280];   // ao (640) then own FF1 cols
    __shared__ __align__(16) float pp[3840];    // QKV K-split partials / cls1 partials
    __shared__ float sc[224];
    __shared__ float stats[32];
    __shared__ float biasK[16];

    const f4* xs4 = reinterpret_cast<const f4*>(xs);
    const f4* loc4 = reinterpret_cast<const f4*>(loc);
    const f4* res4 = reinterpret_cast<const f4*>(res);
    const f4* h1a4 = reinterpret_cast<const f4*>(h1a);

    // ---------------- prologue ----------------
    for (int i = tid; i < 1024; i += 512) loc[i] = pooled[(size_t)b * 1024 + i];
    if (tid < 16) biasK[tid] = biasW[b * 16 + tid];
    __syncthreads();

    // img-proj: own 64 cols x 4 scales -> tokG rows 6..9
    if (tid < 256) {
        const int i = tid >> 6, cl = tid & 63;
        const int c = qt * 64 + cl;
        const f4* w4 = reinterpret_cast<const f4*>(wH + IPW_OFF + ((size_t)(i * 256 + c)) * 256);
        float acc = 0.f;
        #pragma unroll 4
        for (int k8 = 0; k8 < 32; k8++)
            acc += dot8h(w4[k8], loc4[i * 64 + 2 * k8], loc4[i * 64 + 2 * k8 + 1]);
        tokG[(size_t)b * 2560 + (6 + i) * 256 + c] = acc + ipb[i * 256 + c];
    }
    qsync(&flags[0], tid);
    for (int i = tid; i < 2560; i += 512) xs[i] = tokG[(size_t)b * 2560 + i];
    __syncthreads();

    for (int l = 0; l < 2; l++) {
        // ---- QKV own 192 cols (q|k|v of own 2 heads), Ksplit2 — local ----
        if (tid < 384) {
            const int ks = tid / 192, cl = tid % 192;
            const int m = cl >> 6;
            const int gc = m * 256 + qt * 64 + (cl & 63);
            const f4* w4 = reinterpret_cast<const f4*>(wH + INW_OFF + ((size_t)l * 768 + gc) * 256 + ks * 128);
            float acc[NT];
            #pragma unroll
            for (int r = 0; r < NT; r++) acc[r] = 0.f;
            for (int k8 = 0; k8 < 16; k8++) {
                f4 wv4 = w4[k8];
                const int xi = ks * 32 + 2 * k8;
                #pragma unroll
                for (int r = 0; r < NT; r++)
                    acc[r] += dot8h(wv4, xs4[r * 64 + xi], xs4[r * 64 + xi + 1]);
            }
            #pragma unroll
            for (int r = 0; r < NT; r++) pp[ks * 1920 + r * 192 + cl] = acc[r];
        }
        __syncthreads();
        for (int i = tid; i < 1920; i += 512) {
            int r = i / 192, cl = i - r * 192;
            int m = cl >> 6, gc = m * 256 + qt * 64 + (cl & 63);
            loc[i] = pp[i] + pp[1920 + i] + inb[l * 768 + gc];
        }
        __syncthreads();

        // ---- scores (2 own heads) — local ----
        if (tid < 200) {
            int hl = tid / 100, rem = tid - 100 * hl;
            int qr = rem / 10, kr = rem - 10 * qr;
            const float* qp = &loc[qr * 192 + hl * 32];
            const float* kp = &loc[kr * 192 + 64 + hl * 32];
            float s = 0.f;
            #pragma unroll
            for (int d = 0; d < 32; d++) s += qp[d] * kp[d];
            sc[tid] = s * 0.17677669529663687f + biasK[kr];
        }
        __syncthreads();
        if (tid < 20) {
            float* row = &sc[tid * 10];
            float m = row[0];
            #pragma unroll
            for (int k = 1; k < 10; k++) m = fmaxf(m, row[k]);
            float ss = 0.f;
            #pragma unroll
            for (int k = 0; k < 10; k++) { float e = expf(row[k] - m); row[k] = e; ss += e; }
            float inv = 1.f / ss;
            #pragma unroll
            for (int k = 0; k < 10; k++) row[k] *= inv;
        }
        __syncthreads();

        // ---- AV -> ao own 64 cols, kept in LDS (h1a[0..640)) ----
        for (int idx = tid; idx < 640; idx += 512) {   // FIX: strided (640 > 512)
            int hl = idx / 320, rem = idx - 320 * hl;
            int r = rem >> 5, c = rem & 31;
            float s = 0.f;
            #pragma unroll
            for (int kr = 0; kr < 10; kr++)
                s += sc[hl * 100 + r * 10 + kr] * loc[kr * 192 + 128 + hl * 32 + c];
            h1a[r * 64 + hl * 32 + c] = s;
        }
        __syncthreads();

        // ---- out_proj PARTIALS: all 256 cols, K = own 64 ao cols ----
        {
            const int c = tid & 255, rh = tid >> 8;   // rows rh*5..rh*5+5
            const f4* w4 = reinterpret_cast<const f4*>(wH + OW_OFF + ((size_t)l * 256 + c) * 256 + qt * 64);
            float acc[5];
            #pragma unroll
            for (int rr = 0; rr < 5; rr++) acc[rr] = 0.f;
            for (int k8 = 0; k8 < 8; k8++) {
                f4 wv4 = w4[k8];
                #pragma unroll
                for (int rr = 0; rr < 5; rr++) {
                    int r = rh * 5 + rr;
                    acc[rr] += dot8h(wv4, h1a4[r * 16 + 2 * k8], h1a4[r * 16 + 2 * k8 + 1]);
                }
            }
            #pragma unroll
            for (int rr = 0; rr < 5; rr++)
                opW[((size_t)(b * 4 + qt)) * 2560 + (rh * 5 + rr) * 256 + c] = acc[rr];
        }
        qsync(&flags[1 + 2 * l], tid);

        // ---- sum partials + bias + residual -> res ; LN1 -> xs ----
        for (int i = tid; i < 2560; i += 512) {
            float v = opW[(size_t)(b * 4 + 0) * 2560 + i] + opW[(size_t)(b * 4 + 1) * 2560 + i]
                    + opW[(size_t)(b * 4 + 2) * 2560 + i] + opW[(size_t)(b * 4 + 3) * 2560 + i]
                    + ob[l * 256 + (i & 255)] + xs[i];
            res[i] = v;
        }
        __syncthreads();
        for (int r = wv; r < NT; r += 8) {
            float v0 = res[r * 256 + lane], v1 = res[r * 256 + 64 + lane];
            float v2 = res[r * 256 + 128 + lane], v3 = res[r * 256 + 192 + lane];
            float s = wred(v0 + v1 + v2 + v3);
            float q = wred(v0 * v0 + v1 * v1 + v2 * v2 + v3 * v3);
            if (lane == 0) {
                float m = s * (1.f / 256.f);
                stats[r] = m;
                stats[16 + r] = rsqrtf(fmaxf(q * (1.f / 256.f) - m * m, 0.f) + 1e-5f);
            }
        }
        __syncthreads();
        for (int i = tid; i < 2560; i += 512) {
            int r = i >> 8, c = i & 255;
            xs[i] = (res[i] - stats[r]) * stats[16 + r] * n1w[l * 256 + c] + n1b[l * 256 + c];
        }
        __syncthreads();

        // ---- FF1 own 128 cols, full K=256 — local -> h1a ----
        if (tid < 256) {
            const int cl = tid & 127, rh = (tid >> 7) & 1;
            const int gc = qt * 128 + cl;
            const f4* w4 = reinterpret_cast<const f4*>(wH + L1W_OFF + ((size_t)l * 512 + gc) * 256);
            float acc[5];
            #pragma unroll
            for (int rr = 0; rr < 5; rr++) acc[rr] = 0.f;
            for (int k8 = 0; k8 < 32; k8++) {
                f4 wv4 = w4[k8];
                #pragma unroll
                for (int rr = 0; rr < 5; rr++) {
                    int r = rh * 5 + rr;
                    acc[rr] += dot8h(wv4, xs4[r * 64 + 2 * k8], xs4[r * 64 + 2 * k8 + 1]);
                }
            }
            float bb = l1b[l * 512 + gc];
            #pragma unroll
            for (int rr = 0; rr < 5; rr++)
                h1a[(rh * 5 + rr) * 128 + cl] = fmaxf(acc[rr] + bb, 0.f);
        }
        __syncthreads();

        // ---- FF2 PARTIALS: all 256 cols, K = own 128 h1 cols ----
        {
            const int c = tid & 255, rh = tid >> 8;
            const f4* w4 = reinterpret_cast<const f4*>(wH + L2W_OFF + ((size_t)l * 256 + c) * 512 + qt * 128);
            float acc[5];
            #pragma unroll
            for (int rr = 0; rr < 5; rr++) acc[rr] = 0.f;
            for (int k8 = 0; k8 < 16; k8++) {
                f4 wv4 = w4[k8];
                #pragma unroll
                for (int rr = 0; rr < 5; rr++) {
                    int r = rh * 5 + rr;
                    acc[rr] += dot8h(wv4, h1a4[r * 32 + 2 * k8], h1a4[r * 32 + 2 * k8 + 1]);
                }
            }
            #pragma unroll
            for (int rr = 0; rr < 5; rr++)
                f2W[((size_t)(b * 4 + qt)) * 2560 + (rh * 5 + rr) * 256 + c] = acc[rr];
        }
        qsync(&flags[2 + 2 * l], tid);

        // ---- sum partials + bias + residual -> res ; LN2 -> xs ----
        for (int i = tid; i < 2560; i += 512) {
            float v = f2W[(size_t)(b * 4 + 0) * 2560 + i] + f2W[(size_t)(b * 4 + 1) * 2560 + i]
                    + f2W[(size_t)(b * 4 + 2) * 2560 + i] + f2W[(size_t)(b * 4 + 3) * 2560 + i]
                    + l2b[l * 256 + (i & 255)] + xs[i];
            res[i] = v;
        }
        __syncthreads();
        for (int r = wv; r < NT; r += 8) {
            float v0 = res[r * 256 + lane], v1 = res[r * 256 + 64 + lane];
            float v2 = res[r * 256 + 128 + lane], v3 = res[r * 256 + 192 + lane];
            float s = wred(v0 + v1 + v2 + v3);
            float q = wred(v0 * v0 + v1 * v1 + v2 * v2 + v3 * v3);
            if (lane == 0) {
                float m = s * (1.f / 256.f);
                stats[r] = m;
                stats[16 + r] = rsqrtf(fmaxf(q * (1.f / 256.f) - m * m, 0.f) + 1e-5f);
            }
        }
        __syncthreads();
        for (int i = tid; i < 2560; i += 512) {
            int r = i >> 8, c = i & 255;
            xs[i] = (res[i] - stats[r]) * stats[16 + r] * n2w[l * 256 + c] + n2b[l * 256 + c];
        }
        __syncthreads();
    }

    // ---------------- epilogue ----------------
    // masked mean pool -> res[0..256) (ct)
    if (tid < 256) {
        float len = 0.f, s = 0.f;
        #pragma unroll
        for (int r = 0; r < NT; r++) {
            float v = (biasK[r] == 0.f) ? 1.f : 0.f;
            len += v;
            s += v * xs[r * 256 + tid];
        }
        res[tid] = s / fmaxf(len, 1.f);
    }
    __syncthreads();

    // cls1 own 128 cols, Ksplit2 -> hW
    if (tid < 256) {
        const int kh = tid >> 7, cl = tid & 127;
        const int gc = qt * 128 + cl;
        const f4* w4 = reinterpret_cast<const f4*>(wH + C1W_OFF + (size_t)gc * 256 + kh * 128);
        float acc = 0.f;
        #pragma unroll 4
        for (int k8 = 0; k8 < 16; k8++)
            acc += dot8h(w4[k8], res4[kh * 32 + 2 * k8], res4[kh * 32 + 2 * k8 + 1]);
        pp[kh * 128 + cl] = acc;
    }
    __syncthreads();
    if (tid < 128) {
        const int gc = qt * 128 + tid;
        hW[(size_t)b * 512 + gc] = fmaxf(pp[tid] + pp[128 + tid] + c1b[gc], 0.f);
    }
    qsync(&flags[5], tid);
    for (int i = tid; i < 512; i += 512) res[i] = hW[(size_t)b * 512 + i];
    __syncthreads();

    // cls2 own 99 outputs, full K=512
    if (tid < 99) {
        const int o = qt * 99 + tid;
        const f4* w4 = reinterpret_cast<const f4*>(wH + C2W_OFF + (size_t)o * 512);
        float acc = 0.f;
        #pragma unroll 4
        for (int k8 = 0; k8 < 64; k8++)
            acc += dot8h(w4[k8], res4[2 * k8], res4[2 * k8 + 1]);
        out[(size_t)b * NCL + o] = acc + c2b[o];
    }
}

// ---------------------------------------------------------------------------
extern "C" void kernel_launch(void* const* d_in, const int* in_sizes, int n_in,
                              void* d_out, int out_size, void* d_ws, size_t ws_size,
                              hipStream_t stream)
{
    const float* pred = (const float*)d_in[0];
    const float* hs   = (const float*)d_in[1];
    const float* f0   = (const float*)d_in[2];
    const float* f1   = (const float*)d_in[3];
    const float* f2   = (const float*)d_in[4];
    const float* f3   = (const float*)d_in[5];
    const float* ipw  = (const float*)d_in[6];
    const float* ipb  = (const float*)d_in[7];
    const float* inw  = (const float*)d_in[8];
    const float* inb  = (const float*)d_in[9];
    const float* ow   = (const float*)d_in[10];
    const float* ob   = (const float*)d_in[11];
    const float* l1w  = (const float*)d_in[12];
    const float* l1b  = (const float*)d_in[13];
    const float* l2w  = (const float*)d_in[14];
    const float* l2b  = (const float*)d_in[15];
    const float* ln1w = (const float*)d_in[16];
    const float* ln1b = (const float*)d_in[17];
    const float* ln2w = (const float*)d_in[18];
    const float* ln2b = (const float*)d_in[19];
    const float* c1w  = (const float*)d_in[20];
    const float* c1b  = (const float*)d_in[21];
    const float* c2w  = (const float*)d_in[22];
    const float* c2b  = (const float*)d_in[23];

    float* ws = (float*)d_ws;
    float* pooled = ws;                          //  65536
    float* tokG   = pooled + NB * 4 * ND;        // 163840
    float* biasW  = tokG + NB * 2560;            //   1024
    __half* wH    = (__half*)(biasW + 1024);     // 1644544 halves
    float* opW    = (float*)(wH + TOTW);         // 655360 (64*4*2560)
    float* f2W    = opW + NB * 4 * 2560;         // 655360
    float* hW     = f2W + NB * 4 * 2560;         //  32768
    int*   flagW  = (int*)(hW + NB * 512);       //   1024 ints

    pool_cls_kernel<<<NB + POOL_ROWS + CONV_BLOCKS, 256, 0, stream>>>(
        pred, hs, f0, f1, f2, f3, ipw, inw, ow, l1w, l2w, c1w, c2w,
        pooled, tokG, biasW, wH, flagW);
    xform_kernel<<<4 * NB, 512, 0, stream>>>(
        pooled, tokG, biasW, wH, ipb, inb, ob, l1b, l2b,
        ln1w, ln1b, ln2w, ln2b, c1b, c2b,
        opW, f2W, hW, flagW, (float*)d_out);
}

// Round 21
// 278.306 us; speedup vs baseline: 8.5340x; 1.0170x over previous
//
#include <hip/hip_runtime.h>
#include <hip/hip_fp16.h>
#include <math.h>

#define NB 64
#define NQ 300
#define NP 6
#define ND 256
#define NF 512
#define NCL 396
#define NT 10

// fp16 weight workspace layout (element offsets in halves)
#define IPW_OFF 0
#define INW_OFF 262144
#define OW_OFF  655360
#define L1W_OFF 786432
#define L2W_OFF 1048576
#define C1W_OFF 1310720
#define C2W_OFF 1441792
#define TOTW    1644544
#define CONV_BLOCKS 803
#define POOL_ROWS 65536

typedef float f4 __attribute__((ext_vector_type(4)));

__device__ __forceinline__ float wred(float s) {
    #pragma unroll
    for (int o = 32; o; o >>= 1) s += __shfl_down(s, o, 64);
    return s;
}

__device__ __forceinline__ float dot8h(f4 wv, f4 xlo, f4 xhi) {
    const __half2* hp = reinterpret_cast<const __half2*>(&wv);
    float2 p0 = __half22float2(hp[0]);
    float2 p1 = __half22float2(hp[1]);
    float2 p2 = __half22float2(hp[2]);
    float2 p3 = __half22float2(hp[3]);
    return p0.x * xlo.x + p0.y * xlo.y + p1.x * xlo.z + p1.y * xlo.w
         + p2.x * xhi.x + p2.y * xhi.y + p3.x * xhi.z + p3.y * xhi.w;
}

// 4-sibling spin barrier (device scope; flags zeroed by K1 each call;
// siblings are XCD-local so flag+data traffic stays in one L2).
__device__ __forceinline__ void qsync(int* flag, int tid) {
    __syncthreads();
    if (tid == 0) {
        __threadfence();
        __hip_atomic_fetch_add(flag, 1, __ATOMIC_ACQ_REL, __HIP_MEMORY_SCOPE_AGENT);
        while (__hip_atomic_load(flag, __ATOMIC_ACQUIRE, __HIP_MEMORY_SCOPE_AGENT) < 4)
            __builtin_amdgcn_s_sleep(2);
    }
    __syncthreads();
}

// ---------------------------------------------------------------------------
// K1 (unchanged): cls-pool + feat-pool + fp16 weight conversion.
// ---------------------------------------------------------------------------
__global__ __launch_bounds__(256) void pool_cls_kernel(
    const float* __restrict__ pred, const float* __restrict__ hs,
    const float* __restrict__ f0, const float* __restrict__ f1,
    const float* __restrict__ f2, const float* __restrict__ f3,
    const float* __restrict__ ipw, const float* __restrict__ inw,
    const float* __restrict__ ow, const float* __restrict__ l1w,
    const float* __restrict__ l2w, const float* __restrict__ c1w,
    const float* __restrict__ c2w,
    float* __restrict__ pooled, float* __restrict__ tokG,
    float* __restrict__ biasW, __half* __restrict__ wH,
    int* __restrict__ flagW)
{
    const int bid = blockIdx.x;
    const int tid = threadIdx.x;
    __shared__ float shm[1824];

    if (bid < NB) {
        const int b = bid;
        if (tid < 16) flagW[b * 16 + tid] = 0;
        float* maskL = shm;
        float* countsL = shm + 1800;
        for (int i = tid; i < NQ * NP; i += 256) {
            float x = pred[(size_t)b * NQ * NP + i];
            float sg = 1.f / (1.f + expf(-x));
            maskL[i] = (sg > 0.3f) ? 1.f : 0.f;
        }
        __syncthreads();
        if (tid < NP) {
            float c = 0.f;
            for (int q = 0; q < NQ; q++) c += maskL[q * NP + tid];
            countsL[tid] = c;
        }
        __syncthreads();
        float acc[NP] = {0.f, 0.f, 0.f, 0.f, 0.f, 0.f};
        const float* hsb = hs + (size_t)b * NQ * ND + tid;
        for (int q = 0; q < NQ; q++) {
            float h = hsb[(size_t)q * ND];
            #pragma unroll
            for (int p = 0; p < NP; p++) acc[p] += maskL[q * NP + p] * h;
        }
        bool anyv = false;
        #pragma unroll
        for (int p = 0; p < NP; p++) anyv = anyv || (countsL[p] > 0.f);
        #pragma unroll
        for (int p = 0; p < NP; p++) {
            float cm = acc[p] / fmaxf(countsL[p], 1.f);
            if (p == 0 && !anyv) cm = hs[(size_t)b * NQ * ND + tid];
            tokG[(size_t)b * 1536 + p * ND + tid] = cm;
        }
        if (tid < 16) {
            float bv = 0.f;
            if (tid < NP) {
                bool v = countsL[tid] > 0.f;
                if (tid == 0 && !anyv) v = true;
                bv = v ? 0.f : -1e30f;
            }
            biasW[b * 16 + tid] = bv;
        }
        return;
    }

    if (bid >= NB + POOL_ROWS) {
        const int cid = bid - (NB + POOL_ROWS);
        size_t base = (size_t)cid * 2048 + (size_t)tid * 8;
        const float* src; size_t off;
        if      (base < INW_OFF) { src = ipw; off = IPW_OFF; }
        else if (base < OW_OFF)  { src = inw; off = INW_OFF; }
        else if (base < L1W_OFF) { src = ow;  off = OW_OFF;  }
        else if (base < L2W_OFF) { src = l1w; off = L1W_OFF; }
        else if (base < C1W_OFF) { src = l2w; off = L2W_OFF; }
        else if (base < C2W_OFF) { src = c1w; off = C1W_OFF; }
        else                     { src = c2w; off = C2W_OFF; }
        const f4* s4 = reinterpret_cast<const f4*>(src + (base - off));
        f4 a = s4[0], b2 = s4[1];
        union { __half2 h[4]; f4 v; } u;
        u.h[0] = __floats2half2_rn(a.x, a.y);
        u.h[1] = __floats2half2_rn(a.z, a.w);
        u.h[2] = __floats2half2_rn(b2.x, b2.y);
        u.h[3] = __floats2half2_rn(b2.z, b2.w);
        *reinterpret_cast<f4*>(wH + base) = u.v;
        return;
    }

    const int row = bid - NB;
    const int scale = row >> 14;
    const int rr = row & 16383;
    const int b = rr >> 8;
    const int d = rr & 255;
    const float* src;
    int n;
    switch (scale) {
        case 0: src = f0; n = 96 * 96; break;
        case 1: src = f1; n = 48 * 48; break;
        case 2: src = f2; n = 24 * 24; break;
        default: src = f3; n = 12 * 12; break;
    }
    const f4* p4 = reinterpret_cast<const f4*>(src + ((size_t)b * ND + d) * (size_t)n);
    int n4 = n >> 2;
    float s = 0.f;
    for (int i = tid; i < n4; i += 256) {
        f4 v = __builtin_nontemporal_load(&p4[i]);
        s += v.x + v.y + v.z + v.w;
    }
    s = wred(s);
    int wid = tid >> 6, lane = tid & 63;
    if (lane == 0) shm[wid] = s;
    __syncthreads();
    if (tid == 0) {
        float t = shm[0] + shm[1] + shm[2] + shm[3];
        pooled[((size_t)b * 4 + scale) * ND + d] = t / (float)n;
    }
}

// ---------------------------------------------------------------------------
// K2: column-split transformer, 4 syncs (out_proj + FF2 exchange per layer).
// b = blk & 63, qt = blk >> 6 -> siblings {b, b+64, b+128, b+192} share XCD.
// img-proj and cls1 computed redundantly per-block (no exchange needed).
// ---------------------------------------------------------------------------
__global__ __launch_bounds__(512) void xform_kernel(
    const float* __restrict__ pooled, const float* __restrict__ tokG,
    const float* __restrict__ biasW, const __half* __restrict__ wH,
    const float* __restrict__ ipb, const float* __restrict__ inb,
    const float* __restrict__ ob, const float* __restrict__ l1b,
    const float* __restrict__ l2b,
    const float* __restrict__ n1w, const float* __restrict__ n1b,
    const float* __restrict__ n2w, const float* __restrict__ n2b,
    const float* __restrict__ c1b, const float* __restrict__ c2b,
    float* opW, float* f2W,
    int* flagW, float* __restrict__ out)
{
    const int b  = blockIdx.x & 63;   // XCD-local decode
    const int qt = blockIdx.x >> 6;
    const int tid = threadIdx.x;
    const int lane = tid & 63;
    const int wv = tid >> 6;
    int* flags = flagW + b * 16;

    __shared__ __align__(16) float xs[2560];    // full current x
    __shared__ __align__(16) float loc[1920];   // pld (prologue) / own q|k|v
    __shared__ __align__(16) float res[2560];   // resid / ct+h epilogue
    __shared__ __align__(16) float h1a[1280];   // ao (640) then own FF1 cols
    __shared__ __align__(16) float pp[3840];    // QKV K-split partials
    __shared__ float sc[224];
    __shared__ float stats[32];
    __shared__ float biasK[16];

    const f4* xs4 = reinterpret_cast<const f4*>(xs);
    const f4* loc4 = reinterpret_cast<const f4*>(loc);
    const f4* res4 = reinterpret_cast<const f4*>(res);
    const f4* h1a4 = reinterpret_cast<const f4*>(h1a);

    // ---------------- prologue ----------------
    for (int i = tid; i < 1536; i += 512) xs[i] = tokG[(size_t)b * 1536 + i];
    for (int i = tid; i < 1024; i += 512) loc[i] = pooled[(size_t)b * 1024 + i];
    if (tid < 16) biasK[tid] = biasW[b * 16 + tid];
    __syncthreads();

    // img-proj: ALL 1024 outputs computed locally (2/thread) — no sync needed
    for (int idx = tid; idx < 1024; idx += 512) {
        const int i = idx >> 8, c = idx & 255;
        const f4* w4 = reinterpret_cast<const f4*>(wH + IPW_OFF + ((size_t)(i * 256 + c)) * 256);
        float acc = 0.f;
        #pragma unroll 4
        for (int k8 = 0; k8 < 32; k8++)
            acc += dot8h(w4[k8], loc4[i * 64 + 2 * k8], loc4[i * 64 + 2 * k8 + 1]);
        xs[(6 + i) * 256 + c] = acc + ipb[i * 256 + c];
    }
    __syncthreads();

    for (int l = 0; l < 2; l++) {
        // ---- QKV own 192 cols (q|k|v of own 2 heads), Ksplit2 — local ----
        if (tid < 384) {
            const int ks = tid / 192, cl = tid % 192;
            const int m = cl >> 6;
            const int gc = m * 256 + qt * 64 + (cl & 63);
            const f4* w4 = reinterpret_cast<const f4*>(wH + INW_OFF + ((size_t)l * 768 + gc) * 256 + ks * 128);
            float acc[NT];
            #pragma unroll
            for (int r = 0; r < NT; r++) acc[r] = 0.f;
            for (int k8 = 0; k8 < 16; k8++) {
                f4 wv4 = w4[k8];
                const int xi = ks * 32 + 2 * k8;
                #pragma unroll
                for (int r = 0; r < NT; r++)
                    acc[r] += dot8h(wv4, xs4[r * 64 + xi], xs4[r * 64 + xi + 1]);
            }
            #pragma unroll
            for (int r = 0; r < NT; r++) pp[ks * 1920 + r * 192 + cl] = acc[r];
        }
        __syncthreads();
        for (int i = tid; i < 1920; i += 512) {
            int r = i / 192, cl = i - r * 192;
            int m = cl >> 6, gc = m * 256 + qt * 64 + (cl & 63);
            loc[i] = pp[i] + pp[1920 + i] + inb[l * 768 + gc];
        }
        __syncthreads();

        // ---- scores (2 own heads) — local ----
        if (tid < 200) {
            int hl = tid / 100, rem = tid - 100 * hl;
            int qr = rem / 10, kr = rem - 10 * qr;
            const float* qp = &loc[qr * 192 + hl * 32];
            const float* kp = &loc[kr * 192 + 64 + hl * 32];
            float s = 0.f;
            #pragma unroll
            for (int d = 0; d < 32; d++) s += qp[d] * kp[d];
            sc[tid] = s * 0.17677669529663687f + biasK[kr];
        }
        __syncthreads();
        if (tid < 20) {
            float* row = &sc[tid * 10];
            float m = row[0];
            #pragma unroll
            for (int k = 1; k < 10; k++) m = fmaxf(m, row[k]);
            float ss = 0.f;
            #pragma unroll
            for (int k = 0; k < 10; k++) { float e = expf(row[k] - m); row[k] = e; ss += e; }
            float inv = 1.f / ss;
            #pragma unroll
            for (int k = 0; k < 10; k++) row[k] *= inv;
        }
        __syncthreads();

        // ---- AV -> ao own 64 cols, kept in LDS (h1a[0..640)) ----
        for (int idx = tid; idx < 640; idx += 512) {
            int hl = idx / 320, rem = idx - 320 * hl;
            int r = rem >> 5, c = rem & 31;
            float s = 0.f;
            #pragma unroll
            for (int kr = 0; kr < 10; kr++)
                s += sc[hl * 100 + r * 10 + kr] * loc[kr * 192 + 128 + hl * 32 + c];
            h1a[r * 64 + hl * 32 + c] = s;
        }
        __syncthreads();

        // ---- out_proj PARTIALS: all 256 cols, K = own 64 ao cols ----
        {
            const int c = tid & 255, rh = tid >> 8;
            const f4* w4 = reinterpret_cast<const f4*>(wH + OW_OFF + ((size_t)l * 256 + c) * 256 + qt * 64);
            float acc[5];
            #pragma unroll
            for (int rr = 0; rr < 5; rr++) acc[rr] = 0.f;
            for (int k8 = 0; k8 < 8; k8++) {
                f4 wv4 = w4[k8];
                #pragma unroll
                for (int rr = 0; rr < 5; rr++) {
                    int r = rh * 5 + rr;
                    acc[rr] += dot8h(wv4, h1a4[r * 16 + 2 * k8], h1a4[r * 16 + 2 * k8 + 1]);
                }
            }
            #pragma unroll
            for (int rr = 0; rr < 5; rr++)
                opW[((size_t)(b * 4 + qt)) * 2560 + (rh * 5 + rr) * 256 + c] = acc[rr];
        }
        qsync(&flags[0 + 2 * l], tid);

        // ---- sum partials + bias + residual -> res ; LN1 -> xs ----
        for (int i = tid; i < 2560; i += 512) {
            float v = opW[(size_t)(b * 4 + 0) * 2560 + i] + opW[(size_t)(b * 4 + 1) * 2560 + i]
                    + opW[(size_t)(b * 4 + 2) * 2560 + i] + opW[(size_t)(b * 4 + 3) * 2560 + i]
                    + ob[l * 256 + (i & 255)] + xs[i];
            res[i] = v;
        }
        __syncthreads();
        for (int r = wv; r < NT; r += 8) {
            float v0 = res[r * 256 + lane], v1 = res[r * 256 + 64 + lane];
            float v2 = res[r * 256 + 128 + lane], v3 = res[r * 256 + 192 + lane];
            float s = wred(v0 + v1 + v2 + v3);
            float q = wred(v0 * v0 + v1 * v1 + v2 * v2 + v3 * v3);
            if (lane == 0) {
                float m = s * (1.f / 256.f);
                stats[r] = m;
                stats[16 + r] = rsqrtf(fmaxf(q * (1.f / 256.f) - m * m, 0.f) + 1e-5f);
            }
        }
        __syncthreads();
        for (int i = tid; i < 2560; i += 512) {
            int r = i >> 8, c = i & 255;
            xs[i] = (res[i] - stats[r]) * stats[16 + r] * n1w[l * 256 + c] + n1b[l * 256 + c];
        }
        __syncthreads();

        // ---- FF1 own 128 cols, full K=256 — local -> h1a ----
        if (tid < 256) {
            const int cl = tid & 127, rh = (tid >> 7) & 1;
            const int gc = qt * 128 + cl;
            const f4* w4 = reinterpret_cast<const f4*>(wH + L1W_OFF + ((size_t)l * 512 + gc) * 256);
            float acc[5];
            #pragma unroll
            for (int rr = 0; rr < 5; rr++) acc[rr] = 0.f;
            for (int k8 = 0; k8 < 32; k8++) {
                f4 wv4 = w4[k8];
                #pragma unroll
                for (int rr = 0; rr < 5; rr++) {
                    int r = rh * 5 + rr;
                    acc[rr] += dot8h(wv4, xs4[r * 64 + 2 * k8], xs4[r * 64 + 2 * k8 + 1]);
                }
            }
            float bb = l1b[l * 512 + gc];
            #pragma unroll
            for (int rr = 0; rr < 5; rr++)
                h1a[(rh * 5 + rr) * 128 + cl] = fmaxf(acc[rr] + bb, 0.f);
        }
        __syncthreads();

        // ---- FF2 PARTIALS: all 256 cols, K = own 128 h1 cols ----
        {
            const int c = tid & 255, rh = tid >> 8;
            const f4* w4 = reinterpret_cast<const f4*>(wH + L2W_OFF + ((size_t)l * 256 + c) * 512 + qt * 128);
            float acc[5];
            #pragma unroll
            for (int rr = 0; rr < 5; rr++) acc[rr] = 0.f;
            for (int k8 = 0; k8 < 16; k8++) {
                f4 wv4 = w4[k8];
                #pragma unroll
                for (int rr = 0; rr < 5; rr++) {
                    int r = rh * 5 + rr;
                    acc[rr] += dot8h(wv4, h1a4[r * 32 + 2 * k8], h1a4[r * 32 + 2 * k8 + 1]);
                }
            }
            #pragma unroll
            for (int rr = 0; rr < 5; rr++)
                f2W[((size_t)(b * 4 + qt)) * 2560 + (rh * 5 + rr) * 256 + c] = acc[rr];
        }
        qsync(&flags[1 + 2 * l], tid);

        // ---- sum partials + bias + residual -> res ; LN2 -> xs ----
        for (int i = tid; i < 2560; i += 512) {
            float v = f2W[(size_t)(b * 4 + 0) * 2560 + i] + f2W[(size_t)(b * 4 + 1) * 2560 + i]
                    + f2W[(size_t)(b * 4 + 2) * 2560 + i] + f2W[(size_t)(b * 4 + 3) * 2560 + i]
                    + l2b[l * 256 + (i & 255)] + xs[i];
            res[i] = v;
        }
        __syncthreads();
        for (int r = wv; r < NT; r += 8) {
            float v0 = res[r * 256 + lane], v1 = res[r * 256 + 64 + lane];
            float v2 = res[r * 256 + 128 + lane], v3 = res[r * 256 + 192 + lane];
            float s = wred(v0 + v1 + v2 + v3);
            float q = wred(v0 * v0 + v1 * v1 + v2 * v2 + v3 * v3);
            if (lane == 0) {
                float m = s * (1.f / 256.f);
                stats[r] = m;
                stats[16 + r] = rsqrtf(fmaxf(q * (1.f / 256.f) - m * m, 0.f) + 1e-5f);
            }
        }
        __syncthreads();
        for (int i = tid; i < 2560; i += 512) {
            int r = i >> 8, c = i & 255;
            xs[i] = (res[i] - stats[r]) * stats[16 + r] * n2w[l * 256 + c] + n2b[l * 256 + c];
        }
        __syncthreads();
    }

    // ---------------- epilogue (fully local; no syncs) ----------------
    // masked mean pool -> res[0..256) (ct)
    if (tid < 256) {
        float len = 0.f, s = 0.f;
        #pragma unroll
        for (int r = 0; r < NT; r++) {
            float v = (biasK[r] == 0.f) ? 1.f : 0.f;
            len += v;
            s += v * xs[r * 256 + tid];
        }
        res[tid] = s / fmaxf(len, 1.f);
    }
    __syncthreads();

    // cls1: ALL 512 outputs computed locally (1/thread, K=256)
    {
        const int c = tid;
        const f4* w4 = reinterpret_cast<const f4*>(wH + C1W_OFF + (size_t)c * 256);
        float acc = 0.f;
        #pragma unroll 4
        for (int k8 = 0; k8 < 32; k8++)
            acc += dot8h(w4[k8], res4[2 * k8], res4[2 * k8 + 1]);
        float hv = fmaxf(acc + c1b[c], 0.f);
        __syncthreads();            // all ct reads done before writing res[512..)
        res[512 + c] = hv;
    }
    __syncthreads();

    // cls2: own 99 outputs, full K=512
    if (tid < 99) {
        const int o = qt * 99 + tid;
        const f4* w4 = reinterpret_cast<const f4*>(wH + C2W_OFF + (size_t)o * 512);
        const f4* h4 = reinterpret_cast<const f4*>(res + 512);
        float acc = 0.f;
        #pragma unroll 4
        for (int k8 = 0; k8 < 64; k8++)
            acc += dot8h(w4[k8], h4[2 * k8], h4[2 * k8 + 1]);
        out[(size_t)b * NCL + o] = acc + c2b[o];
    }
}

// ---------------------------------------------------------------------------
extern "C" void kernel_launch(void* const* d_in, const int* in_sizes, int n_in,
                              void* d_out, int out_size, void* d_ws, size_t ws_size,
                              hipStream_t stream)
{
    const float* pred = (const float*)d_in[0];
    const float* hs   = (const float*)d_in[1];
    const float* f0   = (const float*)d_in[2];
    const float* f1   = (const float*)d_in[3];
    const float* f2   = (const float*)d_in[4];
    const float* f3   = (const float*)d_in[5];
    const float* ipw  = (const float*)d_in[6];
    const float* ipb  = (const float*)d_in[7];
    const float* inw  = (const float*)d_in[8];
    const float* inb  = (const float*)d_in[9];
    const float* ow   = (const float*)d_in[10];
    const float* ob   = (const float*)d_in[11];
    const float* l1w  = (const float*)d_in[12];
    const float* l1b  = (const float*)d_in[13];
    const float* l2w  = (const float*)d_in[14];
    const float* l2b  = (const float*)d_in[15];
    const float* ln1w = (const float*)d_in[16];
    const float* ln1b = (const float*)d_in[17];
    const float* ln2w = (const float*)d_in[18];
    const float* ln2b = (const float*)d_in[19];
    const float* c1w  = (const float*)d_in[20];
    const float* c1b  = (const float*)d_in[21];
    const float* c2w  = (const float*)d_in[22];
    const float* c2b  = (const float*)d_in[23];

    float* ws = (float*)d_ws;
    float* pooled = ws;                          //  65536
    float* tokG   = pooled + NB * 4 * ND;        //  98304 (rows 0..5 only)
    float* biasW  = tokG + NB * 1536;            //   1024
    __half* wH    = (__half*)(biasW + 1024);     // 1644544 halves
    float* opW    = (float*)(wH + TOTW);         // 655360 (64*4*2560)
    float* f2W    = opW + NB * 4 * 2560;         // 655360
    int*   flagW  = (int*)(f2W + NB * 4 * 2560); //   1024 ints

    pool_cls_kernel<<<NB + POOL_ROWS + CONV_BLOCKS, 256, 0, stream>>>(
        pred, hs, f0, f1, f2, f3, ipw, inw, ow, l1w, l2w, c1w, c2w,
        pooled, tokG, biasW, wH, flagW);
    xform_kernel<<<4 * NB, 512, 0, stream>>>(
        pooled, tokG, biasW, wH, ipb, inb, ob, l1b, l2b,
        ln1w, ln1b, ln2w, ln2b, c1b, c2b,
        opW, f2W, flagW, (float*)d_out);
}